// Round 15
// baseline (339.825 us; speedup 1.0000x reference)
//
#include <hip/hip_runtime.h>

// Problem constants
#define DIMD   256
#define NTOK   16384
#define NCODE  8192
#define NELEM  (NTOK * DIMD)

// fp32 project-GEMM tiling (R14: 64x128 tiles, 256 blocks = 1/CU)
#define PBM 64
#define PBK 128
#define BD 32
#define PAD 4
#define SA (PBM + PAD)
#define SB (PBK + PAD)

// distance kernels — per-pass measured-best structures:
//   dist_min : shared-B (R10) — 4 waves share a 1024-code slice, B DMA'd
//              to LDS dbuf, 1 barrier/group (divergence-free).
//   dist_emit: private-B (R9/R13), EM_SPLITS=2, barrier-free. R15: the
//              fp32 rescore is FOLDED into emit's tail — each block
//              rescoreds its own ebuf hits (16-lane-group dot, packed
//              atomicMin to fin). Global list/cnt/rescore dispatch gone.
//              minkey is already global after pass 1, so per-block
//              thresholds are final and per-block rescore is complete.
// Dead ends (measured): forced occupancy (R1 spills), fused emission
//   (R0/2/3), device atomics in loop (R4: 425us), acc-split ILP (R6
//   spills), 32-tok/wave (R7), per-wave async LDS (R8), shared-B emit
//   (R10), cooperative grid-sync fusion (R12: harness core-dump).
#define MARGIN 0.5f                   // > two-sided worst-case bf16 distance error
#define EBUF_CAP 1024                 // per-block staging (expected ~100 hits)

// shared-B (min) geometry
#define CODES_PER_BLOCK 1024
#define TOK_PER_BLOCK   256
#define MIN_NGROUPS (CODES_PER_BLOCK / 16)      // 64
// private-B (emit) geometry
#define EM_SPLITS 2
#define EM_CPW (NCODE / EM_SPLITS / 4)          // 1024
#define EM_NGROUPS (EM_CPW / 16)                // 64

#define PROJ_BLOCKS ((NCODE / PBM) * (DIMD / PBK))   // 256
#define CONV_BLOCKS (NTOK / 4)                       // 4096

typedef float floatx4 __attribute__((ext_vector_type(4)));
typedef short short8  __attribute__((ext_vector_type(8)));
typedef unsigned int u32;

__device__ __forceinline__ unsigned short f2bf(float f) {
    unsigned u = __float_as_uint(f);
    unsigned r = (u + 0x7FFFu + ((u >> 16) & 1u)) >> 16;
    return (unsigned short)r;
}

// async 16B/lane global->LDS DMA: dest = wave-uniform base + lane*16 (linear)
__device__ __forceinline__ void gl_lds16(const void* g, void* l) {
    __builtin_amdgcn_global_load_lds(
        (const __attribute__((address_space(1))) u32*)g,
        (__attribute__((address_space(3))) u32*)l, 16, 0, 0);
}

// monotone float<->uint key (handles negative partial distances)
__device__ __forceinline__ unsigned fkey(float f) {
    unsigned u = __float_as_uint(f);
    return (u & 0x80000000u) ? ~u : (u | 0x80000000u);
}
__device__ __forceinline__ float funkey(unsigned k) {
    unsigned u = (k & 0x80000000u) ? (k & 0x7FFFFFFFu) : ~k;
    return __uint_as_float(u);
}

// fragment-major Cb index for element (row=code, col=k)
__device__ __forceinline__ size_t cb2_idx(int row, int col) {
    return ((size_t)((row >> 4) * 8 + (col >> 5))) * 512
         + (size_t)((((col >> 3) & 3) * 16 + (row & 15)) * 8 + (col & 7));
}

// -------------------------------------------------------------------------
// Kernel 1 (fused prep): blocks [0,256) = codebook projection; blocks
// [256, 256+4096) = convx + inits (fin/minkey; loss slot).
// -------------------------------------------------------------------------
__global__ __launch_bounds__(256, 3)
void prep_kernel(const float* __restrict__ E, const float* __restrict__ W,
                 const float* __restrict__ bias, float* __restrict__ C,
                 unsigned short* __restrict__ Cb2,
                 float* __restrict__ cnormA, float* __restrict__ cnormB,
                 const float* __restrict__ X, float* __restrict__ xnorm,
                 unsigned short* __restrict__ Xb,
                 unsigned long long* __restrict__ fin,
                 unsigned* __restrict__ minkey, float* __restrict__ out)
{
    __shared__ float smem[BD * SA + BD * SB];

    const int bid = blockIdx.x;
    const int tid = threadIdx.x;

    if (bid >= PROJ_BLOCKS) {
        // ---- convx part + inits ----
        const int row0 = (bid - PROJ_BLOCKS) * 4;
        const int wave = tid >> 6;
        const int lane = tid & 63;
        const int row  = row0 + wave;
        float4 v = *(const float4*)&X[(size_t)row * DIMD + lane * 4];
        ushort4 h = {f2bf(v.x), f2bf(v.y), f2bf(v.z), f2bf(v.w)};
        *(ushort4*)&Xb[(size_t)row * DIMD + lane * 4] = h;
        float s = v.x * v.x + v.y * v.y + v.z * v.z + v.w * v.w;
#pragma unroll
        for (int off = 1; off < 64; off <<= 1) s += __shfl_xor(s, off);
        if (lane == 0) xnorm[row] = s;
        if (tid < 4) {
            fin[row0 + tid]    = ~0ull;
            minkey[row0 + tid] = ~0u;
        }
        if (bid == PROJ_BLOCKS && tid == 0) out[NELEM] = 0.f;
        return;
    }

    // ---- project part: 64-row x 128-col tile ----
    float* As = smem;
    float* Bs = smem + BD * SA;

    const int tx  = tid & 15;
    const int ty  = tid >> 4;
    const int m0  = (bid & 127) * PBM;
    const int j0  = (bid >> 7) * PBK;

    const int srow = tid >> 3;
    const int scol = (tid & 7) * 4;

    float acc[4][8];
#pragma unroll
    for (int i = 0; i < 4; ++i)
#pragma unroll
        for (int j = 0; j < 8; ++j) acc[i][j] = 0.f;

    for (int dc = 0; dc < DIMD / BD; ++dc) {
        const int d0 = dc * BD;
        __syncthreads();
#pragma unroll
        for (int rr = 0; rr < 2; ++rr) {
            const int r = srow + rr * 32;
            float4 av = *(const float4*)&E[(size_t)(m0 + r) * DIMD + d0 + scol];
            As[(scol + 0) * SA + r] = av.x;
            As[(scol + 1) * SA + r] = av.y;
            As[(scol + 2) * SA + r] = av.z;
            As[(scol + 3) * SA + r] = av.w;
        }
#pragma unroll
        for (int rr = 0; rr < 4; ++rr) {
            const int r = srow + rr * 32;
            float4 bv = *(const float4*)&W[(size_t)(j0 + r) * DIMD + d0 + scol];
            Bs[(scol + 0) * SB + r] = bv.x;
            Bs[(scol + 1) * SB + r] = bv.y;
            Bs[(scol + 2) * SB + r] = bv.z;
            Bs[(scol + 3) * SB + r] = bv.w;
        }
        __syncthreads();
#pragma unroll 4
        for (int d = 0; d < BD; ++d) {
            float4 a0 = *(float4*)&As[d * SA + ty * 4];
            float4 b0 = *(float4*)&Bs[d * SB + tx * 4];
            float4 b1 = *(float4*)&Bs[d * SB + 64 + tx * 4];
            float a[4] = {a0.x, a0.y, a0.z, a0.w};
            float b[8] = {b0.x, b0.y, b0.z, b0.w, b1.x, b1.y, b1.z, b1.w};
#pragma unroll
            for (int i = 0; i < 4; ++i)
#pragma unroll
                for (int j = 0; j < 8; ++j) acc[i][j] = fmaf(a[i], b[j], acc[i][j]);
        }
    }

    __syncthreads();
    float* red = smem;                     // [64 rows][16 tx]

    float4 bja = *(const float4*)&bias[j0 + tx * 4];
    float4 bjb = *(const float4*)&bias[j0 + 64 + tx * 4];
#pragma unroll
    for (int i = 0; i < 4; ++i) {
        const int mloc = ty * 4 + i;
        const int row  = m0 + mloc;
        const size_t rbase = (size_t)row * DIMD;
        float o[8] = {acc[i][0] + bja.x, acc[i][1] + bja.y, acc[i][2] + bja.z, acc[i][3] + bja.w,
                      acc[i][4] + bjb.x, acc[i][5] + bjb.y, acc[i][6] + bjb.z, acc[i][7] + bjb.w};
        *(float4*)&C[rbase + j0 + tx * 4]      = *(float4*)&o[0];
        *(float4*)&C[rbase + j0 + 64 + tx * 4] = *(float4*)&o[4];
        ushort4 h0 = {f2bf(o[0]), f2bf(o[1]), f2bf(o[2]), f2bf(o[3])};
        ushort4 h1 = {f2bf(o[4]), f2bf(o[5]), f2bf(o[6]), f2bf(o[7])};
        *(ushort4*)&Cb2[cb2_idx(row, j0 + tx * 4)]      = h0;
        *(ushort4*)&Cb2[cb2_idx(row, j0 + 64 + tx * 4)] = h1;
        float p = 0.f;
#pragma unroll
        for (int j = 0; j < 8; ++j) p = fmaf(o[j], o[j], p);
        red[mloc * 16 + tx] = p;
    }
    __syncthreads();
    if (tid < 64) {
        float s = 0.f;
#pragma unroll
        for (int k = 0; k < 16; ++k) s += red[tid * 16 + k];
        float* dst = (j0 == 0) ? cnormA : cnormB;
        dst[m0 + tid] = s;
    }
}

// -------------------------------------------------------------------------
// Kernel 2a: PASS 1 — min-GEMM, SHARED-B (R10 measured-best form).
// -------------------------------------------------------------------------
__global__ __launch_bounds__(256, 2)
void dist_min_kernel(const unsigned short* __restrict__ Xb,
                     const unsigned short* __restrict__ Cb2,
                     const float* __restrict__ cnormA,
                     const float* __restrict__ cnormB,
                     unsigned* __restrict__ minkey)
{
    __shared__ short Bls[2][4096];
    __shared__ float cnl[CODES_PER_BLOCK];

    const int tid  = threadIdx.x;
    const int lane = tid & 63;
    const int wv   = tid >> 6;
    const int l15  = lane & 15;
    const int quad = lane >> 4;
    const int tok0 = blockIdx.x * TOK_PER_BLOCK + wv * 64;
    const int cbase = blockIdx.y * CODES_PER_BLOCK;

    {
        const int t4 = tid * 4;
        float4 va = *(const float4*)&cnormA[cbase + t4];
        float4 vb = *(const float4*)&cnormB[cbase + t4];
        cnl[t4 + 0] = va.x + vb.x;
        cnl[t4 + 1] = va.y + vb.y;
        cnl[t4 + 2] = va.z + vb.z;
        cnl[t4 + 3] = va.w + vb.w;
    }

    const unsigned short* bsrc = Cb2 + (size_t)cbase * DIMD;
    auto STAGE = [&](int g) {
        const unsigned short* s = bsrc + (size_t)g * 4096 + wv * 1024 + lane * 8;
        short* d = &Bls[g & 1][wv * 1024];
        gl_lds16(s,       d);
        gl_lds16(s + 512, d + 512);
    };
    STAGE(0);
    STAGE(1);

    short8 a[4][8];
#pragma unroll
    for (int i = 0; i < 4; ++i) {
        const unsigned short* ap = Xb + (size_t)(tok0 + i * 16 + l15) * DIMD + quad * 8;
#pragma unroll
        for (int ks = 0; ks < 8; ++ks)
            a[i][ks] = *(const short8*)(ap + ks * 32);
    }

    float runv[16];
#pragma unroll
    for (int s = 0; s < 16; ++s) runv[s] = 3.4e38f;

    __syncthreads();

    for (int g = 0; g < MIN_NGROUPS; ++g) {
        const short* bp = &Bls[g & 1][lane * 8];
        short8 bc[8];
#pragma unroll
        for (int ks = 0; ks < 8; ++ks) bc[ks] = *(const short8*)(bp + ks * 512);
        const float cnc = cnl[g * 16 + l15];

        floatx4 acc[4];
#pragma unroll
        for (int i = 0; i < 4; ++i) acc[i] = (floatx4){0.f, 0.f, 0.f, 0.f};
#pragma unroll
        for (int ks = 0; ks < 8; ++ks)
#pragma unroll
            for (int i = 0; i < 4; ++i)
                acc[i] = __builtin_amdgcn_mfma_f32_16x16x32_bf16(a[i][ks], bc[ks], acc[i], 0, 0, 0);

#pragma unroll
        for (int i = 0; i < 4; ++i)
#pragma unroll
            for (int r = 0; r < 4; ++r)
                runv[i * 4 + r] = fminf(runv[i * 4 + r], fmaf(-2.f, acc[i][r], cnc));

        __syncthreads();
        if (g + 2 < MIN_NGROUPS) STAGE(g + 2);
    }

#pragma unroll
    for (int s = 0; s < 16; ++s) {
        float m = runv[s];
#pragma unroll
        for (int off = 1; off < 16; off <<= 1) m = fminf(m, __shfl_xor(m, off));
        runv[s] = m;
    }
    if (l15 == 0) {
#pragma unroll
        for (int i = 0; i < 4; ++i)
#pragma unroll
            for (int r = 0; r < 4; ++r)
                atomicMin(&minkey[tok0 + i * 16 + quad * 4 + r], fkey(runv[i * 4 + r]));
    }
}

// -------------------------------------------------------------------------
// Kernel 2b: PASS 2 — emit + IN-BLOCK fp32 rescore (R15). Private-B reg-
// dbuf loop (R9/R13 form) finds hits vs the FINAL global threshold into
// ebuf; tail rescoreds them (16-lane-group dot) with packed atomicMin to
// fin. Overflow (pos >= cap, practically unreachable) rescoreds inline
// (scalar fp32 dot) — correctness never depends on the cap.
// -------------------------------------------------------------------------
__global__ __launch_bounds__(256, 2)
void dist_emit_kernel(const unsigned short* __restrict__ Xb,
                      const unsigned short* __restrict__ Cb2,
                      const float* __restrict__ cnormA,
                      const float* __restrict__ cnormB,
                      const unsigned* __restrict__ minkey,
                      const float* __restrict__ X, const float* __restrict__ C,
                      const float* __restrict__ xnorm,
                      unsigned long long* __restrict__ fin)
{
    __shared__ float tokthr[64];
    __shared__ unsigned ebuf[EBUF_CAP];
    __shared__ unsigned ecnt;

    const int tid  = threadIdx.x;
    const int lane = tid & 63;
    const int wv   = tid >> 6;
    const int l15  = lane & 15;
    const int quad = lane >> 4;
    const int tok0 = blockIdx.x * 64;
    const int cbase = blockIdx.y * (NCODE / EM_SPLITS) + wv * EM_CPW;

    if (tid == 0) ecnt = 0;
    if (tid < 64) tokthr[tid] = funkey(minkey[tok0 + tid]) + MARGIN;
    __syncthreads();

    short8 a[4][8];
#pragma unroll
    for (int i = 0; i < 4; ++i) {
        const unsigned short* ap = Xb + (size_t)(tok0 + i * 16 + l15) * DIMD + quad * 8;
#pragma unroll
        for (int ks = 0; ks < 8; ++ks)
            a[i][ks] = *(const short8*)(ap + ks * 32);
    }

    float thr[16];
#pragma unroll
    for (int i = 0; i < 4; ++i)
#pragma unroll
        for (int r = 0; r < 4; ++r)
            thr[i * 4 + r] = tokthr[i * 16 + quad * 4 + r];

    const unsigned short* bp0 = Cb2 + (size_t)cbase * DIMD + lane * 8;

    short8 breg[2][8];
    float  cnr[2];
#pragma unroll
    for (int ks = 0; ks < 8; ++ks) breg[0][ks] = *(const short8*)(bp0 + ks * 512);
    cnr[0] = cnormA[cbase + l15] + cnormB[cbase + l15];

    auto group_body = [&](int g, short8 (&bc)[8], short8 (&bn)[8],
                          float cnc, float& cnn) {
        const int code0 = cbase + g * 16;
        if (g + 1 < EM_NGROUPS) {
            const unsigned short* bpn = bp0 + (size_t)(g + 1) * 4096;
#pragma unroll
            for (int ks = 0; ks < 8; ++ks) bn[ks] = *(const short8*)(bpn + ks * 512);
            const int cnx = code0 + 16 + l15;
            cnn = cnormA[cnx] + cnormB[cnx];
        }

        floatx4 acc[4];
#pragma unroll
        for (int i = 0; i < 4; ++i) acc[i] = (floatx4){0.f, 0.f, 0.f, 0.f};
#pragma unroll
        for (int ks = 0; ks < 8; ++ks)
#pragma unroll
            for (int i = 0; i < 4; ++i)
                acc[i] = __builtin_amdgcn_mfma_f32_16x16x32_bf16(a[i][ks], bc[ks], acc[i], 0, 0, 0);

        unsigned mask = 0;
#pragma unroll
        for (int i = 0; i < 4; ++i)
#pragma unroll
            for (int r = 0; r < 4; ++r) {
                const float dd = fmaf(-2.f, acc[i][r], cnc);
                if (dd < thr[i * 4 + r]) mask |= (1u << (i * 4 + r));
            }

        if (__any(mask != 0)) {
            if (mask) {
                unsigned pos = atomicAdd(&ecnt, (unsigned)__popc(mask));
#pragma unroll
                for (int i = 0; i < 4; ++i)
#pragma unroll
                    for (int r = 0; r < 4; ++r) {
                        const int s = i * 4 + r;
                        if (mask & (1u << s)) {
                            const unsigned token = tok0 + i * 16 + quad * 4 + r;
                            const unsigned codeX = (unsigned)(code0 + l15);
                            if (pos < EBUF_CAP) {
                                ebuf[pos] = (token << 13) | codeX;
                            } else {
                                // overflow: inline scalar fp32 rescore (never in practice)
                                const float* xr = &X[(size_t)token * DIMD];
                                const float* cr = &C[(size_t)codeX * DIMD];
                                float dot = 0.f;
                                for (int d = 0; d < DIMD; ++d) dot = fmaf(xr[d], cr[d], dot);
                                const float ddf = xnorm[token] + (cnormA[codeX] + cnormB[codeX]) - 2.f * dot;
                                atomicMin(&fin[token],
                                          ((unsigned long long)__float_as_uint(ddf) << 32) | codeX);
                            }
                            ++pos;
                        }
                    }
            }
        }
    };

    for (int gg = 0; gg < EM_NGROUPS; gg += 2) {
        group_body(gg,     breg[0], breg[1], cnr[0], cnr[1]);
        group_body(gg + 1, breg[1], breg[0], cnr[1], cnr[0]);
    }

    // ---- in-block fp32 rescore of staged hits (16-lane groups) ----
    __syncthreads();
    const unsigned n = (ecnt < EBUF_CAP) ? ecnt : EBUF_CAP;
    const int g16 = lane & 15;
    const int grp = wv * 4 + (lane >> 4);      // 0..15
    for (unsigned c = grp; c < n; c += 16) {
        const unsigned e = ebuf[c];
        const unsigned tok = e >> 13, code = e & 8191u;
        const float* xr = &X[(size_t)tok * DIMD];
        const float* cr = &C[(size_t)code * DIMD];
        float dot = 0.f;
#pragma unroll
        for (int r = 0; r < 4; ++r) {
            float4 x4 = *(const float4*)&xr[r * 64 + g16 * 4];
            float4 c4 = *(const float4*)&cr[r * 64 + g16 * 4];
            dot = fmaf(x4.x, c4.x, dot);
            dot = fmaf(x4.y, c4.y, dot);
            dot = fmaf(x4.z, c4.z, dot);
            dot = fmaf(x4.w, c4.w, dot);
        }
#pragma unroll
        for (int d = 1; d < 16; d <<= 1) dot += __shfl_xor(dot, d);
        if (g16 == 0) {
            const float dd = xnorm[tok] + (cnormA[code] + cnormB[code]) - 2.f * dot;
            const unsigned long long p =
                ((unsigned long long)__float_as_uint(dd) << 32) | code;
            atomicMin(&fin[tok], p);
        }
    }
}

// -------------------------------------------------------------------------
// Kernel 3: gather winner, straight-through output, loss. One atomic/block.
// -------------------------------------------------------------------------
__global__ __launch_bounds__(256)
void finalize_kernel(const float* __restrict__ X, const float* __restrict__ C,
                     const unsigned long long* __restrict__ fin,
                     float* __restrict__ out)
{
    __shared__ float part[4];
    const int lane = threadIdx.x & 63;
    const int wv   = threadIdx.x >> 6;
    const int t0   = blockIdx.x * 64;

    float local = 0.f;
    for (int it = 0; it < 16; ++it) {
        const int t = t0 + wv * 16 + it;
        const unsigned code = (unsigned)(fin[t] & 0xFFFFFFFFull);
        float4 c4 = *(const float4*)&C[(size_t)code * DIMD + lane * 4];
        float4 x4 = *(const float4*)&X[(size_t)t * DIMD + lane * 4];
        float4 w  = {c4.x - x4.x, c4.y - x4.y, c4.z - x4.z, c4.w - x4.w};
        local += w.x * w.x + w.y * w.y + w.z * w.z + w.w * w.w;
        float4 zq = {x4.x + w.x, x4.y + w.y, x4.z + w.z, x4.w + w.w};
        *(float4*)&out[(size_t)t * DIMD + lane * 4] = zq;
        if (lane == 0) out[NELEM + 1 + t] = (float)code;
    }
#pragma unroll
    for (int off = 1; off < 64; off <<= 1) local += __shfl_xor(local, off);
    if (lane == 0) part[wv] = local;
    __syncthreads();
    if (threadIdx.x == 0) {
        const float s = part[0] + part[1] + part[2] + part[3];
        atomicAdd(&out[NELEM], s * (1.25f / (float)NELEM));
    }
}

// -------------------------------------------------------------------------
extern "C" void kernel_launch(void* const* d_in, const int* in_sizes, int n_in,
                              void* d_out, int out_size, void* d_ws, size_t ws_size,
                              hipStream_t stream)
{
    const float* X = (const float*)d_in[0];
    const float* E = (const float*)d_in[1];
    const float* W = (const float*)d_in[2];
    const float* b = (const float*)d_in[3];
    float* out = (float*)d_out;

    char* w = (char*)d_ws;
    float* C            = (float*)w;           w += (size_t)NCODE * DIMD * 4;
    unsigned short* Xb  = (unsigned short*)w;  w += (size_t)NTOK * DIMD * 2;
    unsigned short* Cb2 = (unsigned short*)w;  w += (size_t)NCODE * DIMD * 2;
    float* xnorm        = (float*)w;           w += (size_t)NTOK * 4;
    float* cnormA       = (float*)w;           w += (size_t)NCODE * 4;
    float* cnormB       = (float*)w;           w += (size_t)NCODE * 4;
    unsigned long long* fin = (unsigned long long*)w; w += (size_t)NTOK * 8;
    unsigned* minkey    = (unsigned*)w;        w += (size_t)NTOK * 4;
    (void)ws_size;

    // 4 dispatches, zero memsets, no global candidate list.
    prep_kernel<<<PROJ_BLOCKS + CONV_BLOCKS, 256, 0, stream>>>(
        E, W, b, C, Cb2, cnormA, cnormB, X, xnorm, Xb, fin, minkey, out);
    dist_min_kernel<<<dim3(NTOK / TOK_PER_BLOCK, NCODE / CODES_PER_BLOCK), 256, 0, stream>>>(
        Xb, Cb2, cnormA, cnormB, minkey);
    dist_emit_kernel<<<dim3(NTOK / 64, EM_SPLITS), 256, 0, stream>>>(
        Xb, Cb2, cnormA, cnormB, minkey, X, C, xnorm, fin);
    finalize_kernel<<<NTOK / 64, 256, 0, stream>>>(X, C, fin, out);
}

// Round 17
// 265.238 us; speedup vs baseline: 1.2812x; 1.2812x over previous
//
#include <hip/hip_runtime.h>

// Problem constants
#define DIMD   256
#define NTOK   16384
#define NCODE  8192
#define NELEM  (NTOK * DIMD)

// fp32 project-GEMM tiling (R14: 64x128 tiles, 256 blocks = 1/CU)
#define PBM 64
#define PBK 128
#define BD 32
#define PAD 4
#define SA (PBM + PAD)    // A tile stride (col-major [col][row])
#define SB (PBK + PAD)    // B tile stride

// distance kernels — per-pass measured-best structures (FINAL, R14):
//   dist_min : shared-B (R10) — 4 waves share a 1024-code slice, B DMA'd
//              to LDS dbuf, 1 barrier/group (divergence-free).
//   dist_emit: private-B (R9/R13) — per-wave register B-dbuf, barrier-
//              free, EM_SPLITS=2 (512 blocks = one occupancy round).
// Dead ends (all measured): forced occupancy (R1 spills), fused emission
//   (R0/2/3), device atomics in loop (R4: 425us), acc-split ILP (R6
//   spills), 32-tok/wave (R7 halves intensity), per-wave async LDS (R8),
//   shared-B emit (R10), cooperative grid-sync fusion (R12: harness
//   core-dump), in-block rescore fusion (R15: inline overflow path in
//   hot loop wrecks regalloc — MfmaUtil 34->16%, WRITE 0.2->26MB).
// R16 was an infrastructure failure (container), not a kernel result;
// this is the R14 measured-best source resubmitted unchanged (267.3us).
#define MARGIN 0.5f                   // > two-sided worst-case bf16 distance error
#define EBUF_CAP 1024                 // per-block emit staging

// shared-B (min) geometry
#define CODES_PER_BLOCK 1024
#define TOK_PER_BLOCK   256
#define MIN_NGROUPS (CODES_PER_BLOCK / 16)      // 64
// private-B (emit) geometry
#define EM_SPLITS 2
#define EM_CPW (NCODE / EM_SPLITS / 4)          // 1024
#define EM_NGROUPS (EM_CPW / 16)                // 64

#define PROJ_BLOCKS ((NCODE / PBM) * (DIMD / PBK))   // 256
#define CONV_BLOCKS (NTOK / 4)                       // 4096

typedef float floatx4 __attribute__((ext_vector_type(4)));
typedef short short8  __attribute__((ext_vector_type(8)));
typedef unsigned int u32;

__device__ __forceinline__ unsigned short f2bf(float f) {
    unsigned u = __float_as_uint(f);
    unsigned r = (u + 0x7FFFu + ((u >> 16) & 1u)) >> 16;
    return (unsigned short)r;
}

// async 16B/lane global->LDS DMA: dest = wave-uniform base + lane*16 (linear)
__device__ __forceinline__ void gl_lds16(const void* g, void* l) {
    __builtin_amdgcn_global_load_lds(
        (const __attribute__((address_space(1))) u32*)g,
        (__attribute__((address_space(3))) u32*)l, 16, 0, 0);
}

// monotone float<->uint key (handles negative partial distances)
__device__ __forceinline__ unsigned fkey(float f) {
    unsigned u = __float_as_uint(f);
    return (u & 0x80000000u) ? ~u : (u | 0x80000000u);
}
__device__ __forceinline__ float funkey(unsigned k) {
    unsigned u = (k & 0x80000000u) ? (k & 0x7FFFFFFFu) : ~k;
    return __uint_as_float(u);
}

// fragment-major Cb index for element (row=code, col=k):
// block (row/16, col/32) of 512 elems; within: lane=(colsub/8)*16+(row%16), elem=col%8
__device__ __forceinline__ size_t cb2_idx(int row, int col) {
    return ((size_t)((row >> 4) * 8 + (col >> 5))) * 512
         + (size_t)((((col >> 3) & 3) * 16 + (row & 15)) * 8 + (col & 7));
}

// -------------------------------------------------------------------------
// Kernel 1 (fused prep): blocks [0,256) = codebook projection (64x128
// tiles, 256 blocks = 1/CU); blocks [256, 256+4096) = convx + inits.
// -------------------------------------------------------------------------
__global__ __launch_bounds__(256, 3)
void prep_kernel(const float* __restrict__ E, const float* __restrict__ W,
                 const float* __restrict__ bias, float* __restrict__ C,
                 unsigned short* __restrict__ Cb2,
                 float* __restrict__ cnormA, float* __restrict__ cnormB,
                 const float* __restrict__ X, float* __restrict__ xnorm,
                 unsigned short* __restrict__ Xb,
                 unsigned long long* __restrict__ fin,
                 unsigned* __restrict__ minkey,
                 unsigned* __restrict__ cnt, float* __restrict__ out)
{
    __shared__ float smem[BD * SA + BD * SB];   // 25.6 KB

    const int bid = blockIdx.x;
    const int tid = threadIdx.x;

    if (bid >= PROJ_BLOCKS) {
        // ---- convx part + inits ----
        const int row0 = (bid - PROJ_BLOCKS) * 4;
        const int wave = tid >> 6;
        const int lane = tid & 63;
        const int row  = row0 + wave;
        float4 v = *(const float4*)&X[(size_t)row * DIMD + lane * 4];
        ushort4 h = {f2bf(v.x), f2bf(v.y), f2bf(v.z), f2bf(v.w)};
        *(ushort4*)&Xb[(size_t)row * DIMD + lane * 4] = h;
        float s = v.x * v.x + v.y * v.y + v.z * v.z + v.w * v.w;
#pragma unroll
        for (int off = 1; off < 64; off <<= 1) s += __shfl_xor(s, off);
        if (lane == 0) xnorm[row] = s;
        if (tid < 4) {
            fin[row0 + tid]    = ~0ull;
            minkey[row0 + tid] = ~0u;
        }
        if (bid == PROJ_BLOCKS && tid == 0) { *cnt = 0; out[NELEM] = 0.f; }
        return;
    }

    // ---- project part: 64-row x 128-col tile ----
    float* As = smem;            // [32 cols][SA rows] col-major
    float* Bs = smem + BD * SA;  // [32 cols][SB rows]

    const int tx  = tid & 15;
    const int ty  = tid >> 4;
    const int m0  = (bid & 127) * PBM;
    const int j0  = (bid >> 7) * PBK;

    const int srow = tid >> 3;          // 0..31
    const int scol = (tid & 7) * 4;     // 0..28

    float acc[4][8];
#pragma unroll
    for (int i = 0; i < 4; ++i)
#pragma unroll
        for (int j = 0; j < 8; ++j) acc[i][j] = 0.f;

    for (int dc = 0; dc < DIMD / BD; ++dc) {
        const int d0 = dc * BD;
        __syncthreads();
        // A: 64 rows x 32 cols (2 passes of 32 rows)
#pragma unroll
        for (int rr = 0; rr < 2; ++rr) {
            const int r = srow + rr * 32;
            float4 av = *(const float4*)&E[(size_t)(m0 + r) * DIMD + d0 + scol];
            As[(scol + 0) * SA + r] = av.x;
            As[(scol + 1) * SA + r] = av.y;
            As[(scol + 2) * SA + r] = av.z;
            As[(scol + 3) * SA + r] = av.w;
        }
        // B: 128 rows x 32 cols (4 passes)
#pragma unroll
        for (int rr = 0; rr < 4; ++rr) {
            const int r = srow + rr * 32;
            float4 bv = *(const float4*)&W[(size_t)(j0 + r) * DIMD + d0 + scol];
            Bs[(scol + 0) * SB + r] = bv.x;
            Bs[(scol + 1) * SB + r] = bv.y;
            Bs[(scol + 2) * SB + r] = bv.z;
            Bs[(scol + 3) * SB + r] = bv.w;
        }
        __syncthreads();
#pragma unroll 4
        for (int d = 0; d < BD; ++d) {
            float4 a0 = *(float4*)&As[d * SA + ty * 4];
            float4 b0 = *(float4*)&Bs[d * SB + tx * 4];
            float4 b1 = *(float4*)&Bs[d * SB + 64 + tx * 4];
            float a[4] = {a0.x, a0.y, a0.z, a0.w};
            float b[8] = {b0.x, b0.y, b0.z, b0.w, b1.x, b1.y, b1.z, b1.w};
#pragma unroll
            for (int i = 0; i < 4; ++i)
#pragma unroll
                for (int j = 0; j < 8; ++j) acc[i][j] = fmaf(a[i], b[j], acc[i][j]);
        }
    }

    __syncthreads();                       // done reading As/Bs; reuse smem
    float* red = smem;                     // [64 rows][16 tx]

    float4 bja = *(const float4*)&bias[j0 + tx * 4];
    float4 bjb = *(const float4*)&bias[j0 + 64 + tx * 4];
#pragma unroll
    for (int i = 0; i < 4; ++i) {
        const int mloc = ty * 4 + i;
        const int row  = m0 + mloc;
        const size_t rbase = (size_t)row * DIMD;
        float o[8] = {acc[i][0] + bja.x, acc[i][1] + bja.y, acc[i][2] + bja.z, acc[i][3] + bja.w,
                      acc[i][4] + bjb.x, acc[i][5] + bjb.y, acc[i][6] + bjb.z, acc[i][7] + bjb.w};
        *(float4*)&C[rbase + j0 + tx * 4]      = *(float4*)&o[0];
        *(float4*)&C[rbase + j0 + 64 + tx * 4] = *(float4*)&o[4];
        ushort4 h0 = {f2bf(o[0]), f2bf(o[1]), f2bf(o[2]), f2bf(o[3])};
        ushort4 h1 = {f2bf(o[4]), f2bf(o[5]), f2bf(o[6]), f2bf(o[7])};
        *(ushort4*)&Cb2[cb2_idx(row, j0 + tx * 4)]      = h0;
        *(ushort4*)&Cb2[cb2_idx(row, j0 + 64 + tx * 4)] = h1;
        float p = 0.f;
#pragma unroll
        for (int j = 0; j < 8; ++j) p = fmaf(o[j], o[j], p);
        red[mloc * 16 + tx] = p;
    }
    __syncthreads();
    if (tid < 64) {
        float s = 0.f;
#pragma unroll
        for (int k = 0; k < 16; ++k) s += red[tid * 16 + k];
        float* dst = (j0 == 0) ? cnormA : cnormB;
        dst[m0 + tid] = s;                 // plain store, per-(block,row) unique
    }
}

// -------------------------------------------------------------------------
// Kernel 2a: PASS 1 — min-GEMM, SHARED-B (R10 measured-best form).
// 4 waves × 64 tokens scan the same 1024-code slice; B group (8KB) DMA'd
// into LDS double-buffer, one __syncthreads per group. Direct atomicMin.
// -------------------------------------------------------------------------
__global__ __launch_bounds__(256, 2)
void dist_min_kernel(const unsigned short* __restrict__ Xb,
                     const unsigned short* __restrict__ Cb2,
                     const float* __restrict__ cnormA,
                     const float* __restrict__ cnormB,
                     unsigned* __restrict__ minkey)
{
    __shared__ short Bls[2][4096];             // 16 KB double buffer
    __shared__ float cnl[CODES_PER_BLOCK];     // 4 KB

    const int tid  = threadIdx.x;
    const int lane = tid & 63;
    const int wv   = tid >> 6;
    const int l15  = lane & 15;
    const int quad = lane >> 4;
    const int tok0 = blockIdx.x * TOK_PER_BLOCK + wv * 64;
    const int cbase = blockIdx.y * CODES_PER_BLOCK;

    {
        const int t4 = tid * 4;
        float4 va = *(const float4*)&cnormA[cbase + t4];
        float4 vb = *(const float4*)&cnormB[cbase + t4];
        cnl[t4 + 0] = va.x + vb.x;
        cnl[t4 + 1] = va.y + vb.y;
        cnl[t4 + 2] = va.z + vb.z;
        cnl[t4 + 3] = va.w + vb.w;
    }

    const unsigned short* bsrc = Cb2 + (size_t)cbase * DIMD;
    auto STAGE = [&](int g) {
        const unsigned short* s = bsrc + (size_t)g * 4096 + wv * 1024 + lane * 8;
        short* d = &Bls[g & 1][wv * 1024];
        gl_lds16(s,       d);
        gl_lds16(s + 512, d + 512);
    };
    STAGE(0);
    STAGE(1);

    short8 a[4][8];
#pragma unroll
    for (int i = 0; i < 4; ++i) {
        const unsigned short* ap = Xb + (size_t)(tok0 + i * 16 + l15) * DIMD + quad * 8;
#pragma unroll
        for (int ks = 0; ks < 8; ++ks)
            a[i][ks] = *(const short8*)(ap + ks * 32);
    }

    float runv[16];
#pragma unroll
    for (int s = 0; s < 16; ++s) runv[s] = 3.4e38f;

    __syncthreads();   // cnl + staged groups 0,1 complete

    for (int g = 0; g < MIN_NGROUPS; ++g) {
        const short* bp = &Bls[g & 1][lane * 8];
        short8 bc[8];
#pragma unroll
        for (int ks = 0; ks < 8; ++ks) bc[ks] = *(const short8*)(bp + ks * 512);
        const float cnc = cnl[g * 16 + l15];

        floatx4 acc[4];
#pragma unroll
        for (int i = 0; i < 4; ++i) acc[i] = (floatx4){0.f, 0.f, 0.f, 0.f};
#pragma unroll
        for (int ks = 0; ks < 8; ++ks)
#pragma unroll
            for (int i = 0; i < 4; ++i)
                acc[i] = __builtin_amdgcn_mfma_f32_16x16x32_bf16(a[i][ks], bc[ks], acc[i], 0, 0, 0);

#pragma unroll
        for (int i = 0; i < 4; ++i)
#pragma unroll
            for (int r = 0; r < 4; ++r)
                runv[i * 4 + r] = fminf(runv[i * 4 + r], fmaf(-2.f, acc[i][r], cnc));

        __syncthreads();
        if (g + 2 < MIN_NGROUPS) STAGE(g + 2);
    }

#pragma unroll
    for (int s = 0; s < 16; ++s) {
        float m = runv[s];
#pragma unroll
        for (int off = 1; off < 16; off <<= 1) m = fminf(m, __shfl_xor(m, off));
        runv[s] = m;
    }
    if (l15 == 0) {
#pragma unroll
        for (int i = 0; i < 4; ++i)
#pragma unroll
            for (int r = 0; r < 4; ++r)
                atomicMin(&minkey[tok0 + i * 16 + quad * 4 + r], fkey(runv[i * 4 + r]));
    }
}

// -------------------------------------------------------------------------
// Kernel 2b: PASS 2 — emit vs FINAL threshold, PRIVATE-B register-dbuf
// (R9/R13 measured-best form: barrier-free, EM_SPLITS=2 -> one occupancy
// round). Rare hits staged in block LDS; ONE device atomic per block.
// -------------------------------------------------------------------------
__global__ __launch_bounds__(256, 2)
void dist_emit_kernel(const unsigned short* __restrict__ Xb,
                      const unsigned short* __restrict__ Cb2,
                      const float* __restrict__ cnormA,
                      const float* __restrict__ cnormB,
                      const unsigned* __restrict__ minkey,
                      unsigned* __restrict__ list, unsigned* __restrict__ count,
                      unsigned cap)
{
    __shared__ float tokthr[64];
    __shared__ unsigned ebuf[EBUF_CAP];
    __shared__ unsigned ecnt, gbase;

    const int tid  = threadIdx.x;
    const int lane = tid & 63;
    const int wv   = tid >> 6;
    const int l15  = lane & 15;
    const int quad = lane >> 4;
    const int tok0 = blockIdx.x * 64;
    const int cbase = blockIdx.y * (NCODE / EM_SPLITS) + wv * EM_CPW;

    if (tid == 0) ecnt = 0;
    if (tid < 64) tokthr[tid] = funkey(minkey[tok0 + tid]) + MARGIN;
    __syncthreads();

    short8 a[4][8];
#pragma unroll
    for (int i = 0; i < 4; ++i) {
        const unsigned short* ap = Xb + (size_t)(tok0 + i * 16 + l15) * DIMD + quad * 8;
#pragma unroll
        for (int ks = 0; ks < 8; ++ks)
            a[i][ks] = *(const short8*)(ap + ks * 32);
    }

    float thr[16];
#pragma unroll
    for (int i = 0; i < 4; ++i)
#pragma unroll
        for (int r = 0; r < 4; ++r)
            thr[i * 4 + r] = tokthr[i * 16 + quad * 4 + r];

    const unsigned short* bp0 = Cb2 + (size_t)cbase * DIMD + lane * 8;

    short8 breg[2][8];
    float  cnr[2];
#pragma unroll
    for (int ks = 0; ks < 8; ++ks) breg[0][ks] = *(const short8*)(bp0 + ks * 512);
    cnr[0] = cnormA[cbase + l15] + cnormB[cbase + l15];

    auto group_body = [&](int g, short8 (&bc)[8], short8 (&bn)[8],
                          float cnc, float& cnn) {
        const int code0 = cbase + g * 16;
        if (g + 1 < EM_NGROUPS) {
            const unsigned short* bpn = bp0 + (size_t)(g + 1) * 4096;
#pragma unroll
            for (int ks = 0; ks < 8; ++ks) bn[ks] = *(const short8*)(bpn + ks * 512);
            const int cnx = code0 + 16 + l15;
            cnn = cnormA[cnx] + cnormB[cnx];
        }

        floatx4 acc[4];
#pragma unroll
        for (int i = 0; i < 4; ++i) acc[i] = (floatx4){0.f, 0.f, 0.f, 0.f};
#pragma unroll
        for (int ks = 0; ks < 8; ++ks)
#pragma unroll
            for (int i = 0; i < 4; ++i)
                acc[i] = __builtin_amdgcn_mfma_f32_16x16x32_bf16(a[i][ks], bc[ks], acc[i], 0, 0, 0);

        unsigned mask = 0;
#pragma unroll
        for (int i = 0; i < 4; ++i)
#pragma unroll
            for (int r = 0; r < 4; ++r) {
                const float dd = fmaf(-2.f, acc[i][r], cnc);
                if (dd < thr[i * 4 + r]) mask |= (1u << (i * 4 + r));
            }

        if (__any(mask != 0)) {
            if (mask) {
                unsigned pos = atomicAdd(&ecnt, (unsigned)__popc(mask));
#pragma unroll
                for (int i = 0; i < 4; ++i)
#pragma unroll
                    for (int r = 0; r < 4; ++r) {
                        const int s = i * 4 + r;
                        if (mask & (1u << s)) {
                            const unsigned token = tok0 + i * 16 + quad * 4 + r;
                            const unsigned entry = (token << 13) | (unsigned)(code0 + l15);
                            if (pos < EBUF_CAP) ebuf[pos] = entry;
                            else { unsigned gp = atomicAdd(count, 1u); if (gp < cap) list[gp] = entry; }
                            ++pos;
                        }
                    }
            }
        }
    };

    for (int gg = 0; gg < EM_NGROUPS; gg += 2) {
        group_body(gg,     breg[0], breg[1], cnr[0], cnr[1]);
        group_body(gg + 1, breg[1], breg[0], cnr[1], cnr[0]);
    }

    __syncthreads();
    const unsigned n = (ecnt < EBUF_CAP) ? ecnt : EBUF_CAP;
    if (tid == 0) gbase = atomicAdd(count, n);
    __syncthreads();
    const unsigned gb = gbase;
    for (unsigned i = tid; i < n; i += 256) {
        const unsigned p = gb + i;
        if (p < cap) list[p] = ebuf[i];
    }
}

// -------------------------------------------------------------------------
// Kernel 3: exact fp32 rescore. 16-lane groups, 4 candidates per wave.
// Packed (d_bits<<32 | code) atomicMin -> lowest-index tie-break.
// -------------------------------------------------------------------------
__global__ __launch_bounds__(256)
void rescore_kernel(const float* __restrict__ X, const float* __restrict__ C,
                    const float* __restrict__ xnorm,
                    const float* __restrict__ cnormA,
                    const float* __restrict__ cnormB,
                    const unsigned* __restrict__ list, const unsigned* __restrict__ count,
                    unsigned cap, unsigned long long* __restrict__ fin)
{
    const int lane = threadIdx.x & 63;
    const int g16  = lane & 15;
    const int sub  = lane >> 4;
    const int gid  = ((blockIdx.x * 256 + threadIdx.x) >> 6) * 4 + sub;
    const int ng   = ((gridDim.x * 256) >> 6) * 4;
    unsigned n = *count; if (n > cap) n = cap;

    for (unsigned c = gid; c < n; c += ng) {
        const unsigned e = list[c];
        const unsigned tok = e >> 13, code = e & 8191u;
        const float* xr = &X[(size_t)tok * DIMD];
        const float* cr = &C[(size_t)code * DIMD];
        float dot = 0.f;
#pragma unroll
        for (int r = 0; r < 4; ++r) {
            float4 x4 = *(const float4*)&xr[r * 64 + g16 * 4];
            float4 c4 = *(const float4*)&cr[r * 64 + g16 * 4];
            dot = fmaf(x4.x, c4.x, dot);
            dot = fmaf(x4.y, c4.y, dot);
            dot = fmaf(x4.z, c4.z, dot);
            dot = fmaf(x4.w, c4.w, dot);
        }
#pragma unroll
        for (int d = 1; d < 16; d <<= 1) dot += __shfl_xor(dot, d);
        if (g16 == 0) {
            const float dd = xnorm[tok] + (cnormA[code] + cnormB[code]) - 2.f * dot;
            const unsigned long long p =
                ((unsigned long long)__float_as_uint(dd) << 32) | code;
            atomicMin(&fin[tok], p);
        }
    }
}

// -------------------------------------------------------------------------
// Kernel 4: gather winner, straight-through output, loss. One atomic/block.
// -------------------------------------------------------------------------
__global__ __launch_bounds__(256)
void finalize_kernel(const float* __restrict__ X, const float* __restrict__ C,
                     const unsigned long long* __restrict__ fin,
                     float* __restrict__ out)
{
    __shared__ float part[4];
    const int lane = threadIdx.x & 63;
    const int wv   = threadIdx.x >> 6;
    const int t0   = blockIdx.x * 64;

    float local = 0.f;
    for (int it = 0; it < 16; ++it) {
        const int t = t0 + wv * 16 + it;
        const unsigned code = (unsigned)(fin[t] & 0xFFFFFFFFull);
        float4 c4 = *(const float4*)&C[(size_t)code * DIMD + lane * 4];
        float4 x4 = *(const float4*)&X[(size_t)t * DIMD + lane * 4];
        float4 w  = {c4.x - x4.x, c4.y - x4.y, c4.z - x4.z, c4.w - x4.w};
        local += w.x * w.x + w.y * w.y + w.z * w.z + w.w * w.w;
        float4 zq = {x4.x + w.x, x4.y + w.y, x4.z + w.z, x4.w + w.w};
        *(float4*)&out[(size_t)t * DIMD + lane * 4] = zq;
        if (lane == 0) out[NELEM + 1 + t] = (float)code;
    }
#pragma unroll
    for (int off = 1; off < 64; off <<= 1) local += __shfl_xor(local, off);
    if (lane == 0) part[wv] = local;
    __syncthreads();
    if (threadIdx.x == 0) {
        const float s = part[0] + part[1] + part[2] + part[3];
        atomicAdd(&out[NELEM], s * (1.25f / (float)NELEM));
    }
}

// -------------------------------------------------------------------------
extern "C" void kernel_launch(void* const* d_in, const int* in_sizes, int n_in,
                              void* d_out, int out_size, void* d_ws, size_t ws_size,
                              hipStream_t stream)
{
    const float* X = (const float*)d_in[0];
    const float* E = (const float*)d_in[1];
    const float* W = (const float*)d_in[2];
    const float* b = (const float*)d_in[3];
    float* out = (float*)d_out;

    char* w = (char*)d_ws;
    float* C            = (float*)w;           w += (size_t)NCODE * DIMD * 4;
    unsigned short* Xb  = (unsigned short*)w;  w += (size_t)NTOK * DIMD * 2;
    unsigned short* Cb2 = (unsigned short*)w;  w += (size_t)NCODE * DIMD * 2;
    float* xnorm        = (float*)w;           w += (size_t)NTOK * 4;
    float* cnormA       = (float*)w;           w += (size_t)NCODE * 4;
    float* cnormB       = (float*)w;           w += (size_t)NCODE * 4;
    unsigned* cnt       = (unsigned*)w;        w += 256;
    unsigned long long* fin = (unsigned long long*)w; w += (size_t)NTOK * 8;
    unsigned* minkey    = (unsigned*)w;        w += (size_t)NTOK * 4;
    unsigned* list      = (unsigned*)w;

    size_t used = (size_t)(w - (char*)d_ws);
    size_t avail = (ws_size > used) ? (ws_size - used) / 4 : 0;
    unsigned cap = (unsigned)((avail > 16777216u) ? 16777216u : avail);

    // 5 dispatches, zero memsets.
    prep_kernel<<<PROJ_BLOCKS + CONV_BLOCKS, 256, 0, stream>>>(
        E, W, b, C, Cb2, cnormA, cnormB, X, xnorm, Xb, fin, minkey, cnt, out);
    dist_min_kernel<<<dim3(NTOK / TOK_PER_BLOCK, NCODE / CODES_PER_BLOCK), 256, 0, stream>>>(
        Xb, Cb2, cnormA, cnormB, minkey);
    dist_emit_kernel<<<dim3(NTOK / 64, EM_SPLITS), 256, 0, stream>>>(
        Xb, Cb2, cnormA, cnormB, minkey, list, cnt, cap);
    rescore_kernel<<<1024, 256, 0, stream>>>(X, C, xnorm, cnormA, cnormB, list, cnt, cap, fin);
    finalize_kernel<<<NTOK / 64, 256, 0, stream>>>(X, C, fin, out);
}